// Round 2
// baseline (166.616 us; speedup 1.0000x reference)
//
#include <hip/hip_runtime.h>

typedef __bf16 bf16x8 __attribute__((ext_vector_type(8)));
typedef float f32x4 __attribute__((ext_vector_type(4)));

__device__ __forceinline__ unsigned short f2bf(float f) {
    unsigned int u = __builtin_bit_cast(unsigned int, f);
    u += 0x7fffu + ((u >> 16) & 1u);   // round-to-nearest-even (finite inputs)
    return (unsigned short)(u >> 16);
}

// ---- Kernel 1: s_eff[b][i] = (style[b]·affine_w[i]/sqrt(S) + affine_b[i]) * wg ----
__global__ void k_style(const float* __restrict__ style, const float* __restrict__ aw,
                        const float* __restrict__ ab, float* __restrict__ s_eff) {
    int b = blockIdx.x;
    int i = threadIdx.x;          // 512 threads
    __shared__ float st[512];
    st[i] = style[(b << 9) + i];
    __syncthreads();
    const float4* row = (const float4*)(aw + ((size_t)i << 9));
    float acc = 0.f;
#pragma unroll 4
    for (int k = 0; k < 128; ++k) {
        float4 r = row[k];
        acc += r.x * st[4 * k] + r.y * st[4 * k + 1] + r.z * st[4 * k + 2] + r.w * st[4 * k + 3];
    }
    float s = acc * 0.04419417382415922f + ab[i];     // 1/sqrt(512)
    s_eff[(b << 9) + i] = s * 0.014731391274719739f;  // wg = 1/sqrt(512*9)
}

// ---- Kernel 2: zero the padded NHWC buffer ----
__global__ void k_zero(uint4* __restrict__ p, int n) {
    uint4 z; z.x = z.y = z.z = z.w = 0u;
    for (int i = blockIdx.x * blockDim.x + threadIdx.x; i < n; i += gridDim.x * blockDim.x)
        p[i] = z;
}

// ---- Kernel 3: x (NCHW f32) -> xmod (padded NHWC bf16), modulated by s_eff ----
// xmod layout: [B][66][66][512] bf16, interior at [h+1][w+1]
__global__ __launch_bounds__(256) void k_packx(const float* __restrict__ x,
                                               const float* __restrict__ s_eff,
                                               unsigned short* __restrict__ xmod) {
    int b = blockIdx.z, h = blockIdx.y, i0 = blockIdx.x << 6;
    __shared__ unsigned short tile[64][72];
    int t = threadIdx.x;
    int tw = t & 63, tg = t >> 6;
#pragma unroll
    for (int r = 0; r < 16; ++r) {
        int il = (tg << 4) + r;
        int i = i0 + il;
        float v = x[((((b << 9) + i) << 6) + h) * 64 + tw] * s_eff[(b << 9) + i];
        tile[il][tw] = f2bf(v);
    }
    __syncthreads();
    int ib = (t & 7) << 3;   // channel sub-block (8 bf16 = 16B)
    int wb = t >> 3;         // 0..31
#pragma unroll
    for (int pass = 0; pass < 2; ++pass) {
        int w = wb + (pass << 5);
        union { unsigned short us[8]; uint4 v; } u;
#pragma unroll
        for (int j = 0; j < 8; ++j) u.us[j] = tile[ib + j][w];
        *(uint4*)(xmod + (((size_t)(b * 66 + h + 1) * 66 + (w + 1)) << 9) + i0 + ib) = u.v;
    }
}

// ---- Kernel 4: weight (O,I,3,3 f32) -> wpk (O,9,I bf16) ----
__global__ __launch_bounds__(256) void k_packw(const float* __restrict__ wsrc,
                                               unsigned short* __restrict__ wpk) {
    int o = blockIdx.x;
    for (int i = threadIdx.x; i < 512; i += 256) {
        const float* src = wsrc + (size_t)((o << 9) + i) * 9;
#pragma unroll
        for (int r = 0; r < 9; ++r)
            wpk[((o * 9 + r) << 9) + i] = f2bf(src[r]);
    }
}

// ---- Kernel 5: implicit GEMM conv.  C[o][b,h,w] = sum_{i,kh,kw} W[o][kh,kw][i] * X[b][h+kh][w+kw][i]
// Block tile: 128 (O) x 128 (N = 2 rows x 64 w), 4 waves (2x2), 16x16x32 bf16 MFMA.
__global__ __launch_bounds__(256) void k_conv(const unsigned short* __restrict__ xmod,
                                              const unsigned short* __restrict__ wpk,
                                              float* __restrict__ out) {
    // LDS: Bs = 4 rows x 66 cols x 80B (64B payload: 32ch bf16) = 21120 B
    //      As = 128 m x 80B (64B payload: 32k bf16)             = 10240 B
    __shared__ __attribute__((aligned(128))) unsigned char lds[31360];
    const int ABASE = 21120;
    int bid = blockIdx.x;
    int mt = bid & 3, nt = bid >> 2;
    int b = nt >> 5, h0 = (nt & 31) << 1;   // h0: output row base (also padded-row base)
    int m0 = mt << 7;
    int tid = threadIdx.x;
    int lane = tid & 63;
    int wv = tid >> 6;
    int wave_m = wv & 1, wave_n = wv >> 1;
    int lm = lane & 15, lk = lane >> 4;

    f32x4 acc[4][4] = {};

    for (int ic = 0; ic < 16; ++ic) {       // 16 chunks of 32 channels
        int i0 = ic << 5;
        __syncthreads();                     // previous iter's LDS reads done
        // stage B: rows h0..h0+3, cols 0..65, channels i0..i0+31
        for (int c = tid; c < 1056; c += 256) {
            int cl = c >> 2, sub = c & 3;
            int row = cl / 66;
            int col = cl - row * 66;
            uint4 v = *(const uint4*)(xmod + ((((b * 66 + h0 + row) * 66 + col) << 9) + i0 + (sub << 3)));
            *(uint4*)(lds + row * 5280 + col * 80 + (sub << 4)) = v;
        }
        for (int r = 0; r < 9; ++r) {        // 9 taps = 9 K-steps of 32
            if (r) __syncthreads();          // prior As reads done
            {
                int c = tid;
#pragma unroll
                for (int q = 0; q < 2; ++q, c += 256) {
                    int m = c >> 2, sub = c & 3;
                    uint4 v = *(const uint4*)(wpk + ((((m0 + m) * 9 + r) << 9) + i0 + (sub << 3)));
                    *(uint4*)(lds + ABASE + m * 80 + (sub << 4)) = v;
                }
            }
            __syncthreads();                 // As (and Bs on r==0) ready
            int kh = r / 3;
            int kw = r - kh * 3;
            bf16x8 af[4], bfr[4];
#pragma unroll
            for (int fm = 0; fm < 4; ++fm)
                af[fm] = *(const bf16x8*)(lds + ABASE + ((wave_m << 6) + (fm << 4) + lm) * 80 + (lk << 4));
#pragma unroll
            for (int fn = 0; fn < 4; ++fn) {
                int nl = (wave_n << 6) + (fn << 4) + lm;
                int hl = nl >> 6, w = nl & 63;
                bfr[fn] = *(const bf16x8*)(lds + (hl + kh) * 5280 + (w + kw) * 80 + (lk << 4));
            }
#pragma unroll
            for (int fm = 0; fm < 4; ++fm)
#pragma unroll
                for (int fn = 0; fn < 4; ++fn)
                    acc[fm][fn] = __builtin_amdgcn_mfma_f32_16x16x32_bf16(af[fm], bfr[fn], acc[fm][fn], 0, 0, 0);
        }
    }
    // epilogue: D row=(lk*4+rr) is O, col=lm is N
#pragma unroll
    for (int fm = 0; fm < 4; ++fm) {
        int o = m0 + (wave_m << 6) + (fm << 4) + (lk << 2);
#pragma unroll
        for (int fn = 0; fn < 4; ++fn) {
            int nl = (wave_n << 6) + (fn << 4) + lm;
            int hl = nl >> 6, w = nl & 63;
            float* dst = out + ((((b << 9) + o) << 6) + (h0 + hl)) * 64 + w;
#pragma unroll
            for (int rr = 0; rr < 4; ++rr)
                dst[rr * 4096] = acc[fm][fn][rr];
        }
    }
}

extern "C" void kernel_launch(void* const* d_in, const int* in_sizes, int n_in,
                              void* d_out, int out_size, void* d_ws, size_t ws_size,
                              hipStream_t stream) {
    const float* x      = (const float*)d_in[0];
    const float* style  = (const float*)d_in[1];
    const float* weight = (const float*)d_in[2];
    const float* aff_w  = (const float*)d_in[3];
    const float* aff_b  = (const float*)d_in[4];
    float* out = (float*)d_out;

    // workspace layout
    unsigned short* xmod = (unsigned short*)d_ws;      // 4*66*66*512 = 8,921,088 bf16 (17.8 MB)
    unsigned short* wpk  = xmod + 8921088;             // 512*9*512  = 2,359,296 bf16 (4.7 MB)
    float* s_eff = (float*)((char*)d_ws + 22560768);   // 2048 f32

    hipLaunchKernelGGL(k_style, dim3(4), dim3(512), 0, stream, style, aff_w, aff_b, s_eff);
    hipLaunchKernelGGL(k_zero, dim3(1024), dim3(256), 0, stream, (uint4*)xmod, 1115136);
    hipLaunchKernelGGL(k_packx, dim3(8, 64, 4), dim3(256), 0, stream, x, s_eff, xmod);
    hipLaunchKernelGGL(k_packw, dim3(512), dim3(256), 0, stream, weight, wpk);
    hipLaunchKernelGGL(k_conv, dim3(512), dim3(256), 0, stream, xmod, wpk, out);
}